// Round 4
// baseline (4651.263 us; speedup 1.0000x reference)
//
#include <hip/hip_runtime.h>
#include <math.h>

#define E_ 8192
#define NNODE 1024
#define NCOEF 49
#define MRED 29
#define CC 128
#define C2 256
#define HH 64
#define NHEAD 8
#define ACH 64
#define RESBA 196
#define DDIST_ 512
#define ECHN 128
#define EIN_ 768
#define EXTRA_ 576
#define ALPHACH_ 512
#define RADTOT 4608
#define AMMW 7424   /* 29*256 */
#define MSGW 1856   /* 29*64 */
#define VALW 3712   /* 29*128 */
#define EPB 8

__constant__ int PERM_M_c[MRED] = {0,2,6,11,16,21,26, 3,7,12,17,22,27, 1,5,10,15,20,25, 8,13,18,23,28, 4,9,14,19,24};
__constant__ int RADOFF_c[MRED] = {0,256,512,768,1024,1280,1536,
                                   1792,2048,2304,2560,2816,3072,
                                   1792,2048,2304,2560,2816,3072,
                                   3328,3584,3840,4096,4352,
                                   3328,3584,3840,4096,4352};

__device__ inline float waveSum64(float v){
  #pragma unroll
  for (int d=32; d>0; d>>=1) v += __shfl_xor(v, d, 64);
  return v;
}
__device__ inline float silu_(float x){ return x/(1.f+__expf(-x)); }

// ---------------- prep: SO2 weight transform, permuted grid tables, proj transpose ----
// Folded SO2 weight: Wbig = [[Wr, Wi], [-Wi, Wr]]  (rows: Re|Im inputs, cols: out_re|out_im)
__device__ inline float so2val(const float* __restrict__ w, int idx, int K0, int h){
  int two_h = 2*h; int k = idx/two_h, jj = idx - k*two_h;
  if (jj < h) return (k<K0) ? w[k*two_h + jj] : -w[(k-K0)*two_h + (h+jj)];
  else        return (k<K0) ? w[k*two_h + jj] :  w[(k-K0)*two_h + (jj-h)];
}
__global__ void k_prep(const float* __restrict__ c1m1, const float* __restrict__ c1m2,
                       const float* __restrict__ c2m1, const float* __restrict__ c2m2,
                       const float* __restrict__ tg, const float* __restrict__ fg,
                       const float* __restrict__ pw,
                       float* __restrict__ Wx1, float* __restrict__ Wx2,
                       float* __restrict__ Wx3, float* __restrict__ Wx4,
                       float* __restrict__ tgp, float* __restrict__ fgp, float* __restrict__ pwt)
{
  const int n1 = 3072*768, n2 = 2560*640, n3 = 768*1536, n4 = 640*1280;
  const int ng = RESBA*MRED, np = 7*128*128;
  int total = n1+n2+n3+n4+2*ng+np;
  for (int i = blockIdx.x*blockDim.x+threadIdx.x; i < total; i += gridDim.x*blockDim.x){
    int j = i;
    if (j < n1){ Wx1[j] = so2val(c1m1, j, 1536, 384); continue; } j -= n1;
    if (j < n2){ Wx2[j] = so2val(c1m2, j, 1280, 320); continue; } j -= n2;
    if (j < n3){ Wx3[j] = so2val(c2m1, j,  384, 768); continue; } j -= n3;
    if (j < n4){ Wx4[j] = so2val(c2m2, j,  320, 640); continue; } j -= n4;
    if (j < ng){ int ba=j/MRED,k=j-ba*MRED; tgp[j] = tg[ba*MRED + PERM_M_c[k]]; continue; } j -= ng;
    if (j < ng){ int ba=j/MRED,k=j-ba*MRED; fgp[j] = fg[ba*MRED + PERM_M_c[k]]; continue; } j -= ng;
    { int l = j/16384, r = j-l*16384, v = r>>7, o = r&127; pwt[j] = pw[l*16384 + o*128 + v]; }
  }
}

// ---------------- CSR over tgt ----------------
__global__ void k_csr_count(const int* __restrict__ ei, int* __restrict__ cnt){
  int e = blockIdx.x*256+threadIdx.x;
  if (e < E_) atomicAdd(&cnt[ei[E_+e]], 1);
}
__global__ __launch_bounds__(1024) void k_csr_scan(const int* __restrict__ cnt,
                                                   int* __restrict__ off, int* __restrict__ pos){
  __shared__ int tmp[NNODE];
  int t = threadIdx.x; int v = cnt[t]; tmp[t] = v; __syncthreads();
  for (int d=1; d<NNODE; d<<=1){
    int add = (t>=d) ? tmp[t-d] : 0; __syncthreads();
    tmp[t] += add; __syncthreads();
  }
  int incl = tmp[t]; int excl = incl - v;
  off[t] = excl; pos[t] = excl;
  if (t == NNODE-1) off[NNODE] = incl;
}
__global__ void k_csr_fill(const int* __restrict__ ei, int* __restrict__ pos, int* __restrict__ edges){
  int e = blockIdx.x*256+threadIdx.x;
  if (e < E_){ int t = ei[E_+e]; int p = atomicAdd(&pos[t],1); edges[p] = e; }
}

// ---------------- radial MLP layers 1+2 (fused, 8 edges/block) ----------------
__global__ __launch_bounds__(128) void k_radial(const float* __restrict__ ed, const int* __restrict__ an,
   const int* __restrict__ ei, const float* __restrict__ semb, const float* __restrict__ temb,
   const float* __restrict__ w1, const float* __restrict__ b1, const float* __restrict__ g1, const float* __restrict__ bt1,
   const float* __restrict__ w2, const float* __restrict__ b2, const float* __restrict__ g2, const float* __restrict__ bt2,
   float* __restrict__ h2out)
{
  __shared__ float xs[EPB][EIN_];
  __shared__ float h1s[EPB][ECHN];
  __shared__ int se[EPB], te[EPB];
  __shared__ float rb[EPB][2][2];
  int tid = threadIdx.x; int eb = blockIdx.x*EPB;
  if (tid < EPB){ int e = eb+tid; se[tid] = an[ei[e]]; te[tid] = an[ei[E_+e]]; }
  __syncthreads();
  for (int i = tid; i < EPB*EIN_; i += 128){
    int el = i/EIN_, k = i - el*EIN_; int e = eb+el; float v;
    if (k < DDIST_) v = ed[(size_t)e*DDIST_ + k];
    else if (k < DDIST_+ECHN) v = semb[se[el]*ECHN + (k-DDIST_)];
    else v = temb[te[el]*ECHN + (k-DDIST_-ECHN)];
    xs[el][k] = v;
  }
  __syncthreads();
  int o = tid, lane = tid&63, wv = tid>>6;
  float gv = g1[o], bv = bt1[o], bb = b1[o];
  float acc[EPB];
  #pragma unroll
  for (int e=0;e<EPB;e++) acc[e] = bb;
  for (int k=0;k<EIN_;k++){
    float w = w1[k*ECHN + o];
    #pragma unroll
    for (int e=0;e<EPB;e++) acc[e] = fmaf(xs[e][k], w, acc[e]);
  }
  #pragma unroll
  for (int e=0;e<EPB;e++){
    float s1 = waveSum64(acc[e]);
    float s2 = waveSum64(acc[e]*acc[e]);
    if (lane==0){ rb[e][wv][0]=s1; rb[e][wv][1]=s2; }
  }
  __syncthreads();
  #pragma unroll
  for (int e=0;e<EPB;e++){
    float s1 = rb[e][0][0]+rb[e][1][0];
    float s2 = rb[e][0][1]+rb[e][1][1];
    float mu = s1*(1.f/128.f), var = s2*(1.f/128.f)-mu*mu;
    float a = (acc[e]-mu)*rsqrtf(var+1e-5f)*gv + bv;
    h1s[e][o] = silu_(a);
  }
  __syncthreads();
  float gv2 = g2[o], bv2 = bt2[o], bb2 = b2[o];
  #pragma unroll
  for (int e=0;e<EPB;e++) acc[e] = bb2;
  for (int k=0;k<ECHN;k++){
    float w = w2[k*ECHN + o];
    #pragma unroll
    for (int e=0;e<EPB;e++) acc[e] = fmaf(h1s[e][k], w, acc[e]);
  }
  #pragma unroll
  for (int e=0;e<EPB;e++){
    float s1 = waveSum64(acc[e]);
    float s2 = waveSum64(acc[e]*acc[e]);
    if (lane==0){ rb[e][wv][0]=s1; rb[e][wv][1]=s2; }
  }
  __syncthreads();
  #pragma unroll
  for (int e=0;e<EPB;e++){
    float s1 = rb[e][0][0]+rb[e][1][0];
    float s2 = rb[e][0][1]+rb[e][1][1];
    float mu = s1*(1.f/128.f), var = s2*(1.f/128.f)-mu*mu;
    float a = (acc[e]-mu)*rsqrtf(var+1e-5f)*gv2 + bv2;
    h2out[(size_t)(eb+e)*ECHN + o] = silu_(a);
  }
}

// ---------------- wigner rotate (+PERM_M) * rad, per-edge ----------------
__global__ __launch_bounds__(256) void k_wigmm(const float* __restrict__ x, const int* __restrict__ ei,
    const float* __restrict__ wig, const float* __restrict__ rad, float* __restrict__ Amm, int e0)
{
  int e = e0 + blockIdx.x;
  int c = threadIdx.x;
  int nid = (c < CC) ? ei[e] : ei[E_ + e];
  int cc = c & (CC-1);
  const float* xb = x + (size_t)nid*NCOEF*CC + cc;
  float xr[NCOEF];
  #pragma unroll
  for (int n=0;n<NCOEF;n++) xr[n] = xb[n*CC];
  const float* wb = wig + (size_t)e*MRED*NCOEF;
  const float* rbp = rad + (size_t)blockIdx.x*RADTOT;
  float* ab = Amm + (size_t)blockIdx.x*AMMW;
  #pragma unroll
  for (int mi=0; mi<MRED; mi++){
    const float* wr = wb + PERM_M_c[mi]*NCOEF;
    float acc = 0.f;
    #pragma unroll
    for (int n=0;n<NCOEF;n++) acc = fmaf(wr[n], xr[n], acc);
    ab[mi*C2 + c] = acc * rbp[RADOFF_c[mi] + c];
  }
}

// ---------------- generic fp32 tile GEMM (64x64, 4x4/thread), epilogue functor ------
struct EpiRad { float* out; __device__ void operator()(int m,int n,float v) const {
  out[(size_t)m*RADTOT + n] = v; } };
struct EpiG1 { float* xextra; float* msgbuf; int e0; __device__ void operator()(int m,int n,float v) const {
  int e = e0+m;
  if (n < EXTRA_) xextra[(size_t)e*EXTRA_ + n] = v;
  else msgbuf[(size_t)e*MSGW + (n-EXTRA_)] = v; } };
struct EpiMsg { float* msgbuf; int e0; int off; __device__ void operator()(int m,int n,float v) const {
  msgbuf[(size_t)(e0+m)*MSGW + off + n] = v; } };
struct EpiVal { float* val; const float* alpha; int e0; int off; __device__ void operator()(int m,int n,float v) const {
  int head = ((off+n)&127)>>4;
  float a = alpha[(size_t)(e0+m)*NHEAD + head];
  val[(size_t)m*VALW + off + n] = v*a; } };

template<class Epi>
__global__ __launch_bounds__(256) void gemm64(const float* __restrict__ A, int sA,
     const float* __restrict__ B, int N, int K, const float* __restrict__ bias, Epi epi)
{
  __shared__ float As[16][68];
  __shared__ float Bs[16][68];
  int tid = threadIdx.x;
  int bm = blockIdx.y*64, bn = blockIdx.x*64;
  int ar = tid>>2, ac = (tid&3)*4;
  int br = tid>>4, bc = (tid&15)*4;
  int ty = tid>>4, tx = tid&15;
  float acc[4][4] = {};
  const float* Ap = A + (size_t)(bm+ar)*sA + ac;
  const float* Bp = B + (size_t)br*N + bn + bc;
  // software pipeline: prefetch K-slab k0+16 while computing slab k0
  float4 av = *(const float4*)(Ap);
  float4 bv = *(const float4*)(Bp);
  for (int k0=0; k0<K; k0+=16){
    As[ac+0][ar]=av.x; As[ac+1][ar]=av.y; As[ac+2][ar]=av.z; As[ac+3][ar]=av.w;
    *(float4*)&Bs[br][bc] = bv;
    __syncthreads();
    if (k0+16 < K){
      av = *(const float4*)(Ap + k0 + 16);
      bv = *(const float4*)(Bp + (size_t)(k0+16)*N);
    }
    #pragma unroll
    for (int k=0;k<16;k++){
      float4 a = *(const float4*)&As[k][ty*4];
      float4 b = *(const float4*)&Bs[k][tx*4];
      acc[0][0]=fmaf(a.x,b.x,acc[0][0]); acc[0][1]=fmaf(a.x,b.y,acc[0][1]);
      acc[0][2]=fmaf(a.x,b.z,acc[0][2]); acc[0][3]=fmaf(a.x,b.w,acc[0][3]);
      acc[1][0]=fmaf(a.y,b.x,acc[1][0]); acc[1][1]=fmaf(a.y,b.y,acc[1][1]);
      acc[1][2]=fmaf(a.y,b.z,acc[1][2]); acc[1][3]=fmaf(a.y,b.w,acc[1][3]);
      acc[2][0]=fmaf(a.z,b.x,acc[2][0]); acc[2][1]=fmaf(a.z,b.y,acc[2][1]);
      acc[2][2]=fmaf(a.z,b.z,acc[2][2]); acc[2][3]=fmaf(a.z,b.w,acc[2][3]);
      acc[3][0]=fmaf(a.w,b.x,acc[3][0]); acc[3][1]=fmaf(a.w,b.y,acc[3][1]);
      acc[3][2]=fmaf(a.w,b.z,acc[3][2]); acc[3][3]=fmaf(a.w,b.w,acc[3][3]);
    }
    __syncthreads();
  }
  #pragma unroll
  for (int i=0;i<4;i++){
    #pragma unroll
    for (int j=0;j<4;j++){
      int m = bm+ty*4+i, n = bn+tx*4+j;
      float v = acc[i][j] + (bias ? bias[n] : 0.f);
      epi(m,n,v);
    }
  }
}

// ---------------- attention: LN + gate + logit ----------------
__global__ __launch_bounds__(64) void k_alpha(const float* __restrict__ xextra,
    const float* __restrict__ ag, const float* __restrict__ ab,
    const float* __restrict__ adot, float* __restrict__ logit)
{
  int e = blockIdx.x; int t = threadIdx.x;
  float gv = ag[t], bv = ab[t];
  #pragma unroll
  for (int h=0; h<NHEAD; h++){
    float xv = xextra[(size_t)e*EXTRA_ + h*ACH + t];
    float s1 = waveSum64(xv), s2 = waveSum64(xv*xv);
    float mu = s1*(1.f/64.f), var = s2*(1.f/64.f)-mu*mu;
    float a = (xv-mu)*rsqrtf(var+1e-5f)*gv + bv;
    float sg = 1.f/(1.f+__expf(-a));
    float a2 = 0.6f*a + 0.4f*a*(2.f*sg-1.f);
    float p = a2 * adot[h*ACH + t];
    float ps = waveSum64(p);
    if (t==0) logit[(size_t)e*NHEAD + h] = ps;
  }
}
__global__ __launch_bounds__(64) void k_softmax(const int* __restrict__ coff, const int* __restrict__ cedges,
    const float* __restrict__ logit, float* __restrict__ alpha)
{
  int node = blockIdx.x; int t = threadIdx.x;
  int s = coff[node], en = coff[node+1];
  if (t < NHEAD){
    float m = -1e30f;
    for (int i=s;i<en;i++){ int e = cedges[i]; m = fmaxf(m, logit[(size_t)e*NHEAD+t]); }
    float den = 0.f;
    for (int i=s;i<en;i++){ int e = cedges[i]; den += __expf(logit[(size_t)e*NHEAD+t]-m); }
    den += 1e-16f;
    for (int i=s;i<en;i++){ int e = cedges[i];
      alpha[(size_t)e*NHEAD+t] = __expf(logit[(size_t)e*NHEAD+t]-m)/den; }
  }
}

// ---------------- grid act: to_grid -> silu -> from_grid, in-place on msgbuf -------
__global__ __launch_bounds__(64) void k_grid(float* __restrict__ msgbuf, const float* __restrict__ xextra,
      const float* __restrict__ tgp, const float* __restrict__ fgp)
{
  int e = blockIdx.x; int c = threadIdx.x;
  float* mb = msgbuf + (size_t)e*MSGW;
  float msg[MRED], tens[MRED];
  #pragma unroll
  for (int k=0;k<MRED;k++){ msg[k] = mb[k*HH + c]; tens[k] = 0.f; }
  for (int ba=0; ba<RESBA; ba++){
    const float* tg = tgp + ba*MRED;
    const float* fg = fgp + ba*MRED;
    float g = 0.f;
    #pragma unroll
    for (int k=0;k<MRED;k++) g = fmaf(tg[k], msg[k], g);
    g = silu_(g);
    #pragma unroll
    for (int k=1;k<MRED;k++) tens[k] = fmaf(fg[k], g, tens[k]);
  }
  mb[c] = silu_(xextra[(size_t)e*EXTRA_ + ALPHACH_ + c]);
  #pragma unroll
  for (int k=1;k<MRED;k++) mb[k*HH + c] = tens[k];
}

// ---------------- wigner^T scatter into node (per chunk, CSR-owned rows) -----------
__global__ __launch_bounds__(128) void k_scatter(const int* __restrict__ coff, const int* __restrict__ cedges,
      const float* __restrict__ wig, const float* __restrict__ valc, float* __restrict__ node,
      int e0, int e1)
{
  int nd = blockIdx.x; int c = threadIdx.x;
  int s = coff[nd], en = coff[nd+1];
  float acc[NCOEF];
  #pragma unroll
  for (int q=0;q<NCOEF;q++) acc[q]=0.f;
  bool any=false;
  for (int i=s;i<en;i++){
    int e = cedges[i];
    if (e < e0 || e >= e1) continue;
    any = true;
    const float* vb = valc + (size_t)(e-e0)*VALW + c;
    float v[MRED];
    #pragma unroll
    for (int r=0;r<MRED;r++) v[r] = vb[r*128];
    const float* wb = wig + (size_t)e*MRED*NCOEF;
    #pragma unroll
    for (int r=0;r<MRED;r++){
      const float* wr = wb + PERM_M_c[r]*NCOEF;
      #pragma unroll
      for (int q=0;q<NCOEF;q++) acc[q] = fmaf(wr[q], v[r], acc[q]);
    }
  }
  if (any){
    float* nb = node + (size_t)nd*NCOEF*128 + c;
    #pragma unroll
    for (int q=0;q<NCOEF;q++) nb[q*128] += acc[q];
  }
}

// ---------------- final projection (pwt pre-transposed [l][v][o]) ----------------
__global__ __launch_bounds__(128) void k_proj(const float* __restrict__ node, const float* __restrict__ pwt,
      const float* __restrict__ pb, float* __restrict__ out)
{
  int b = blockIdx.x, l = blockIdx.y;
  int o = threadIdx.x;
  int i0 = l*l; int nrow = 2*l+1;
  __shared__ float ns[13][128];
  for (int r=0;r<nrow;r++) ns[r][o] = node[((size_t)b*NCOEF + i0 + r)*128 + o];
  __syncthreads();
  float acc[13];
  #pragma unroll
  for (int r=0;r<13;r++) acc[r] = (i0+r==0) ? pb[o] : 0.f;
  const float* pw = pwt + (size_t)l*16384 + o;
  for (int v=0;v<128;v++){
    float w = pw[v*128];
    #pragma unroll
    for (int r=0;r<13;r++) if (r<nrow) acc[r] = fmaf(ns[r][v], w, acc[r]);
  }
  #pragma unroll
  for (int r=0;r<13;r++) if (r<nrow) out[((size_t)b*NCOEF + i0 + r)*128 + o] = acc[r];
}

// =======================================================================================
static inline size_t al256(size_t x){ return (x+255)&~(size_t)255; }

extern "C" void kernel_launch(void* const* d_in, const int* in_sizes, int n_in,
                              void* d_out, int out_size, void* d_ws, size_t ws_size,
                              hipStream_t stream) {
  const float* x     = (const float*)d_in[0];
  const int*   an    = (const int*)  d_in[1];
  const float* ed    = (const float*)d_in[2];
  const int*   ei    = (const int*)  d_in[3];
  const float* semb  = (const float*)d_in[4];
  const float* temb  = (const float*)d_in[5];
  const float* w1    = (const float*)d_in[6];
  const float* b1    = (const float*)d_in[7];
  const float* g1    = (const float*)d_in[8];
  const float* bt1   = (const float*)d_in[9];
  const float* w2    = (const float*)d_in[10];
  const float* b2    = (const float*)d_in[11];
  const float* g2    = (const float*)d_in[12];
  const float* bt2   = (const float*)d_in[13];
  const float* w3    = (const float*)d_in[14];
  const float* b3    = (const float*)d_in[15];
  const float* wig   = (const float*)d_in[16];
  const float* c1m0w = (const float*)d_in[17];
  const float* c1m0b = (const float*)d_in[18];
  const float* c1m1w = (const float*)d_in[19];
  const float* c1m2w = (const float*)d_in[20];
  const float* ag    = (const float*)d_in[21];
  const float* abv   = (const float*)d_in[22];
  const float* adot  = (const float*)d_in[23];
  const float* tg    = (const float*)d_in[24];
  const float* fg    = (const float*)d_in[25];
  const float* c2m0w = (const float*)d_in[26];
  const float* c2m0b = (const float*)d_in[27];
  const float* c2m1w = (const float*)d_in[28];
  const float* c2m2w = (const float*)d_in[29];
  const float* pw    = (const float*)d_in[30];
  const float* pb    = (const float*)d_in[31];
  float* out = (float*)d_out;

  char* base = (char*)d_ws;
  size_t off = 0;
  auto allocf = [&](size_t n)->float* { float* p = (float*)(base+off); off += al256(n*sizeof(float)); return p; };
  float* Wx1    = allocf((size_t)3072*768);
  float* Wx2    = allocf((size_t)2560*640);
  float* Wx3    = allocf((size_t)768*1536);
  float* Wx4    = allocf((size_t)640*1280);
  float* tgp    = allocf(RESBA*MRED);
  float* fgp    = allocf(RESBA*MRED);
  float* pwt    = allocf((size_t)7*128*128);
  float* h2b    = allocf((size_t)E_*ECHN);
  float* xextra = allocf((size_t)E_*EXTRA_);
  float* logit  = allocf((size_t)E_*NHEAD);
  float* alphab = allocf((size_t)E_*NHEAD);
  float* msgbuf = allocf((size_t)E_*MSGW);
  int* csr_cnt   = (int*)allocf(NNODE);
  int* csr_off   = (int*)allocf(NNODE+1);
  int* csr_pos   = (int*)allocf(NNODE);
  int* csr_edges = (int*)allocf(E_);
  float* nodeb  = allocf((size_t)NNODE*NCOEF*128);
  size_t fixed_end = off;

  // chunk size: phase-1 temps (rad+Amm) union with phase-3 val
  int CH = 2048;
  for (;;){
    size_t radb = al256((size_t)CH*RADTOT*4);
    size_t ammb = al256((size_t)CH*AMMW*4);
    size_t valb = al256((size_t)CH*VALW*4);
    size_t big = radb+ammb; if (valb > big) big = valb;
    if (fixed_end + big <= ws_size || CH == 256) break;
    CH >>= 1;
  }
  float* rad_c = (float*)(base + fixed_end);
  float* Amm_c = (float*)(base + fixed_end + al256((size_t)CH*RADTOT*4));
  float* val_c = (float*)(base + fixed_end);   // aliases rad_c (disjoint phases)

  // ---- prep + CSR + radial ----
  k_prep<<<2048, 256, 0, stream>>>(c1m1w, c1m2w, c2m1w, c2m2w, tg, fg, pw,
                                   Wx1, Wx2, Wx3, Wx4, tgp, fgp, pwt);
  hipMemsetAsync(csr_cnt, 0, NNODE*sizeof(int), stream);
  k_csr_count<<<E_/256, 256, 0, stream>>>(ei, csr_cnt);
  k_csr_scan<<<1, NNODE, 0, stream>>>(csr_cnt, csr_off, csr_pos);
  k_csr_fill<<<E_/256, 256, 0, stream>>>(ei, csr_pos, csr_edges);
  k_radial<<<E_/EPB, 128, 0, stream>>>(ed, an, ei, semb, temb,
                                       w1, b1, g1, bt1, w2, b2, g2, bt2, h2b);

  // ---- phase 1: per chunk: rad, wigner-rotate, SO2 conv #1 ----
  for (int e0 = 0; e0 < E_; e0 += CH){
    gemm64<EpiRad><<<dim3(RADTOT/64, CH/64), 256, 0, stream>>>(
        h2b + (size_t)e0*ECHN, ECHN, w3, RADTOT, ECHN, b3, EpiRad{rad_c});
    k_wigmm<<<CH, 256, 0, stream>>>(x, ei, wig, rad_c, Amm_c, e0);
    gemm64<EpiG1><<<dim3(1024/64, CH/64), 256, 0, stream>>>(
        Amm_c, AMMW, c1m0w, 1024, 1792, c1m0b, EpiG1{xextra, msgbuf, e0});
    gemm64<EpiMsg><<<dim3(768/64, CH/64), 256, 0, stream>>>(
        Amm_c + 1792, AMMW, Wx1, 768, 3072, nullptr, EpiMsg{msgbuf, e0, 448});
    gemm64<EpiMsg><<<dim3(640/64, CH/64), 256, 0, stream>>>(
        Amm_c + 4864, AMMW, Wx2, 640, 2560, nullptr, EpiMsg{msgbuf, e0, 1216});
  }

  // ---- phase 2: attention softmax + grid activation ----
  k_alpha<<<E_, 64, 0, stream>>>(xextra, ag, abv, adot, logit);
  k_softmax<<<NNODE, 64, 0, stream>>>(csr_off, csr_edges, logit, alphab);
  k_grid<<<E_, 64, 0, stream>>>(msgbuf, xextra, tgp, fgp);

  // ---- phase 3+4: per chunk: SO2 conv #2 (alpha-scaled) + wigner^T scatter ----
  hipMemsetAsync(nodeb, 0, (size_t)NNODE*NCOEF*128*sizeof(float), stream);
  for (int e0 = 0; e0 < E_; e0 += CH){
    gemm64<EpiVal><<<dim3(896/64, CH/64), 256, 0, stream>>>(
        msgbuf + (size_t)e0*MSGW, MSGW, c2m0w, 896, 448, c2m0b, EpiVal{val_c, alphab, e0, 0});
    gemm64<EpiVal><<<dim3(1536/64, CH/64), 256, 0, stream>>>(
        msgbuf + (size_t)e0*MSGW + 448, MSGW, Wx3, 1536, 768, nullptr, EpiVal{val_c, alphab, e0, 896});
    gemm64<EpiVal><<<dim3(1280/64, CH/64), 256, 0, stream>>>(
        msgbuf + (size_t)e0*MSGW + 1216, MSGW, Wx4, 1280, 640, nullptr, EpiVal{val_c, alphab, e0, 2432});
    k_scatter<<<NNODE, 128, 0, stream>>>(csr_off, csr_edges, wig, val_c, nodeb, e0, e0+CH);
  }

  // ---- phase 5: projection ----
  k_proj<<<dim3(NNODE, 7), 128, 0, stream>>>(nodeb, pwt, pb, out);
}